// Round 2
// baseline (47799.872 us; speedup 1.0000x reference)
//
#include <hip/hip_runtime.h>

#define TL 2048

__device__ __forceinline__ float sigf(float x){ return __builtin_amdgcn_rcpf(1.0f + __expf(-x)); }
__device__ __forceinline__ float tanhff(float x){ return fmaf(2.0f, sigf(2.0f*x), -1.0f); }

// butterfly-add across kc lanes: quad_perm xor1 (0xB1), xor2 (0x4E), ds_swizzle xor4
template<int CTRL>
__device__ __forceinline__ float dpp_xadd(float v){
  int s = __builtin_amdgcn_update_dpp(0, __float_as_int(v), CTRL, 0xF, 0xF, true);
  return v + __int_as_float(s);
}
__device__ __forceinline__ float swz4_add(float v){
  int s = __builtin_amdgcn_ds_swizzle(__float_as_int(v), 0x101F);
  return v + __int_as_float(s);
}

// ---------------- Layer 1 scan: H=128, D=2 folded in. grid (BC/2, 2) x 512 thr.
// WG = (dir, batch-pair). thread = (up in [0,64) unit-pair, kc in [0,8)), KS=16.
__global__ __launch_bounds__(512) void scan1_kernel(
    const float* __restrict__ x, const float* __restrict__ Wih,
    const float* __restrict__ Whh, const float* __restrict__ bih,
    const float* __restrict__ bhh, float* __restrict__ out1)
{
  const int tid = threadIdx.x;
  const int dir = blockIdx.y;
  const int b0  = blockIdx.x * 2;
  const int kc  = tid & 7;
  const int up  = tid >> 3;

  // Whh fragments, kc-rotated k order to kill LDS bank conflicts on h reads
  float4 w[8][4];
  const float* Wh = Whh + dir * 65536;
  #pragma unroll
  for (int g = 0; g < 8; ++g){
    const int tgt = g >> 1, par = g & 1;
    const int row = tgt * 128 + up * 2 + par;
    #pragma unroll
    for (int q = 0; q < 4; ++q){
      const int kof = kc * 16 + (((q + kc) & 3) << 2);
      w[g][q] = *(const float4*)(Wh + row * 128 + kof);
    }
  }
  // pointwise-thread params (threads 0..255): x-projection weights + bias
  const int pj = tid & 127, pbd = tid >> 7;
  float xw0[4], xw1[4], xbs[4];
  if (tid < 256){
    #pragma unroll
    for (int tgt = 0; tgt < 4; ++tgt){
      const int row = tgt * 128 + pj;
      xw0[tgt] = Wih[dir * 1024 + row * 2];
      xw1[tgt] = Wih[dir * 1024 + row * 2 + 1];
      xbs[tgt] = bih[dir * 512 + row] + bhh[dir * 512 + row];
    }
  }
  __shared__ __align__(16) float hbuf[2][2][128];  // [parity][bd][unit]
  __shared__ __align__(16) float glds[2][4][128];  // [bd][gate-type][unit]
  if (tid < 256) hbuf[0][tid >> 7][tid & 127] = 0.0f;
  __syncthreads();

  const float* xb = x + (size_t)b0 * TL * 2;
  float cst = 0.0f;  // c for (pbd, pj), threads < 256
  for (int t = 0; t < TL; ++t){
    const int tt  = dir ? (TL - 1 - t) : t;
    const int cur = t & 1;
    const float x00 = xb[tt * 2],          x01 = xb[tt * 2 + 1];
    const float x10 = xb[TL * 2 + tt * 2], x11 = xb[TL * 2 + tt * 2 + 1];

    float acc[2][8];
    #pragma unroll
    for (int bd = 0; bd < 2; ++bd)
      #pragma unroll
      for (int g = 0; g < 8; ++g) acc[bd][g] = 0.0f;

    const float4* h0 = (const float4*)&hbuf[cur][0][0];
    const float4* h1 = (const float4*)&hbuf[cur][1][0];
    #pragma unroll
    for (int q = 0; q < 4; ++q){
      const int idx = kc * 4 + ((q + kc) & 3);
      const float4 hv0 = h0[idx];
      const float4 hv1 = h1[idx];
      #pragma unroll
      for (int g = 0; g < 8; ++g){
        const float4 wv = w[g][q];
        acc[0][g] = fmaf(wv.x, hv0.x, acc[0][g]);
        acc[0][g] = fmaf(wv.y, hv0.y, acc[0][g]);
        acc[0][g] = fmaf(wv.z, hv0.z, acc[0][g]);
        acc[0][g] = fmaf(wv.w, hv0.w, acc[0][g]);
        acc[1][g] = fmaf(wv.x, hv1.x, acc[1][g]);
        acc[1][g] = fmaf(wv.y, hv1.y, acc[1][g]);
        acc[1][g] = fmaf(wv.z, hv1.z, acc[1][g]);
        acc[1][g] = fmaf(wv.w, hv1.w, acc[1][g]);
      }
    }
    // reduce over 8 kc lanes
    #pragma unroll
    for (int bd = 0; bd < 2; ++bd)
      #pragma unroll
      for (int g = 0; g < 8; ++g){
        float v = acc[bd][g];
        v = dpp_xadd<0xB1>(v);
        v = dpp_xadd<0x4E>(v);
        v = swz4_add(v);
        acc[bd][g] = v;
      }
    if (kc == 0){
      #pragma unroll
      for (int bd = 0; bd < 2; ++bd)
        #pragma unroll
        for (int tgt = 0; tgt < 4; ++tgt)
          *(float2*)&glds[bd][tgt][up * 2] =
            make_float2(acc[bd][tgt * 2], acc[bd][tgt * 2 + 1]);
    }
    __syncthreads();
    if (tid < 256){
      const float xa = pbd ? x10 : x00;
      const float xc = pbd ? x11 : x01;
      float pre[4];
      #pragma unroll
      for (int tgt = 0; tgt < 4; ++tgt)
        pre[tgt] = glds[pbd][tgt][pj] + fmaf(xw0[tgt], xa, fmaf(xw1[tgt], xc, xbs[tgt]));
      const float ig = sigf(pre[0]);
      const float fg = sigf(pre[1]);
      const float gg = tanhff(pre[2]);
      const float og = sigf(pre[3]);
      cst = fmaf(fg, cst, ig * gg);
      const float h = og * tanhff(cst);
      hbuf[cur ^ 1][pbd][pj] = h;
      out1[((size_t)(b0 + pbd) * TL + tt) * 256 + dir * 128 + pj] = h;
    }
    __syncthreads();
  }
}

// ---------------- Layer 2 scan: H=64. grid (BC, ndirs) x 512 thr.
// thread = (j in [0,64), kc in [0,8)), KS=8. xs streamed in 8-step LDS chunks.
__global__ __launch_bounds__(512, 4) void scan2_kernel(
    const float* __restrict__ xs, size_t xs_dir_stride, int dir_base,
    const float* __restrict__ Whh, float* __restrict__ out2)
{
  const int tid = threadIdx.x;
  const int dgrp = blockIdx.y;
  const int dir  = dir_base + dgrp;
  const int b    = blockIdx.x;
  const int kc = tid & 7, j = tid >> 3;

  float4 w[4][2];
  const float* Wh = Whh + dir * 16384;
  #pragma unroll
  for (int tgt = 0; tgt < 4; ++tgt){
    const int row = tgt * 64 + j;
    #pragma unroll
    for (int q = 0; q < 2; ++q)
      w[tgt][q] = *(const float4*)(Wh + row * 64 + kc * 8 + q * 4);
  }
  __shared__ __align__(16) float hbuf[2][64];
  __shared__ __align__(16) float glds[4][64];
  __shared__ __align__(16) float xsb[2][8 * 256];

  if (tid < 64) hbuf[0][tid] = 0.0f;
  const float* xsd = xs + (size_t)dgrp * xs_dir_stride + (size_t)b * TL * 256;
  {
    const int ttS0 = dir ? (TL - 8) : 0;
    float4 p0 = *(const float4*)(xsd + (size_t)ttS0 * 256 + tid * 4);
    *(float4*)&xsb[0][tid * 4] = p0;
  }
  __syncthreads();

  float cst = 0.0f;
  int pbuf = 0;
  float4 pf = make_float4(0.f, 0.f, 0.f, 0.f);
  for (int t = 0; t < TL; ++t){
    const int tt   = dir ? (TL - 1 - t) : t;
    const int cur  = t & 1;
    const int slot = dir ? (7 - (t & 7)) : (t & 7);
    if ((t & 7) == 0 && t + 8 < TL){
      const int c1  = (t >> 3) + 1;
      const int ttS = dir ? (TL - 8 * (c1 + 1)) : 8 * c1;
      pf = *(const float4*)(xsd + (size_t)ttS * 256 + tid * 4);
    }
    float acc[4] = {0.f, 0.f, 0.f, 0.f};
    const float4* hv4 = (const float4*)&hbuf[cur][0];
    #pragma unroll
    for (int q = 0; q < 2; ++q){
      const float4 hv = hv4[kc * 2 + q];
      #pragma unroll
      for (int tgt = 0; tgt < 4; ++tgt){
        const float4 wv = w[tgt][q];
        acc[tgt] = fmaf(wv.x, hv.x, acc[tgt]);
        acc[tgt] = fmaf(wv.y, hv.y, acc[tgt]);
        acc[tgt] = fmaf(wv.z, hv.z, acc[tgt]);
        acc[tgt] = fmaf(wv.w, hv.w, acc[tgt]);
      }
    }
    #pragma unroll
    for (int tgt = 0; tgt < 4; ++tgt){
      float v = acc[tgt];
      v = dpp_xadd<0xB1>(v);
      v = dpp_xadd<0x4E>(v);
      v = swz4_add(v);
      acc[tgt] = v;
    }
    if (kc == 0){
      #pragma unroll
      for (int tgt = 0; tgt < 4; ++tgt) glds[tgt][j] = acc[tgt];
    }
    __syncthreads();
    if (tid < 64){
      float pre[4];
      #pragma unroll
      for (int tgt = 0; tgt < 4; ++tgt)
        pre[tgt] = glds[tgt][tid] + xsb[pbuf][slot * 256 + tgt * 64 + tid];
      const float ig = sigf(pre[0]);
      const float fg = sigf(pre[1]);
      const float gg = tanhff(pre[2]);
      const float og = sigf(pre[3]);
      cst = fmaf(fg, cst, ig * gg);
      const float h = og * tanhff(cst);
      hbuf[cur ^ 1][tid] = h;
      out2[((size_t)b * TL + tt) * 128 + dir * 64 + tid] = h;
    }
    if ((t & 7) == 7 && t + 1 < TL){
      *(float4*)&xsb[pbuf ^ 1][tid * 4] = pf;
      pbuf ^= 1;
    }
    __syncthreads();
  }
}

// ---------------- Layer 3 scan: H=16. grid (BC/2, 2) x 64 thr = 2 chains/WG.
// thread = (j in [0,16), kc in [0,4)), KS=4.
__global__ __launch_bounds__(64) void scan3_kernel(
    const float* __restrict__ xs3, size_t xs_dir_stride,
    const float* __restrict__ Whh, float* __restrict__ out3)
{
  const int tid = threadIdx.x;
  const int dir = blockIdx.y;
  const int b0  = blockIdx.x * 2;
  const int kc = tid & 3, j = tid >> 2;

  float4 w[4];
  const float* Wh = Whh + dir * 1024;
  #pragma unroll
  for (int tgt = 0; tgt < 4; ++tgt)
    w[tgt] = *(const float4*)(Wh + (tgt * 16 + j) * 16 + kc * 4);

  __shared__ __align__(16) float hbuf[2][2][16];
  __shared__ __align__(16) float glds[2][4][16];
  __shared__ __align__(16) float xsb[2][2][512];
  if (tid < 32) hbuf[0][tid >> 4][tid & 15] = 0.0f;

  const int bld = tid >> 5, l32 = tid & 31;
  const float* xrow = xs3 + (size_t)dir * xs_dir_stride + (size_t)(b0 + bld) * TL * 64;
  float4 pf[4];
  {
    const int ttS0 = dir ? (TL - 8) : 0;
    #pragma unroll
    for (int i = 0; i < 4; ++i)
      pf[i] = *(const float4*)(xrow + (size_t)ttS0 * 64 + l32 * 4 + i * 128);
    #pragma unroll
    for (int i = 0; i < 4; ++i)
      *(float4*)&xsb[0][bld][l32 * 4 + i * 128] = pf[i];
  }
  __syncthreads();

  float cst = 0.0f;
  int pbuf = 0;
  for (int t = 0; t < TL; ++t){
    const int tt   = dir ? (TL - 1 - t) : t;
    const int cur  = t & 1;
    const int slot = dir ? (7 - (t & 7)) : (t & 7);
    if ((t & 7) == 0 && t + 8 < TL){
      const int c1  = (t >> 3) + 1;
      const int ttS = dir ? (TL - 8 * (c1 + 1)) : 8 * c1;
      #pragma unroll
      for (int i = 0; i < 4; ++i)
        pf[i] = *(const float4*)(xrow + (size_t)ttS * 64 + l32 * 4 + i * 128);
    }
    float acc[2][4];
    #pragma unroll
    for (int bd = 0; bd < 2; ++bd){
      const float4 hv = *(const float4*)&hbuf[cur][bd][kc * 4];
      #pragma unroll
      for (int tgt = 0; tgt < 4; ++tgt){
        float a = 0.f;
        a = fmaf(w[tgt].x, hv.x, a);
        a = fmaf(w[tgt].y, hv.y, a);
        a = fmaf(w[tgt].z, hv.z, a);
        a = fmaf(w[tgt].w, hv.w, a);
        acc[bd][tgt] = a;
      }
    }
    #pragma unroll
    for (int bd = 0; bd < 2; ++bd)
      #pragma unroll
      for (int tgt = 0; tgt < 4; ++tgt){
        float v = acc[bd][tgt];
        v = dpp_xadd<0xB1>(v);
        v = dpp_xadd<0x4E>(v);
        acc[bd][tgt] = v;
      }
    if (kc == 0){
      #pragma unroll
      for (int bd = 0; bd < 2; ++bd)
        #pragma unroll
        for (int tgt = 0; tgt < 4; ++tgt) glds[bd][tgt][j] = acc[bd][tgt];
    }
    __syncthreads();
    if (tid < 32){
      const int bd = tid >> 4, jj = tid & 15;
      float pre[4];
      #pragma unroll
      for (int tgt = 0; tgt < 4; ++tgt)
        pre[tgt] = glds[bd][tgt][jj] + xsb[pbuf][bd][slot * 64 + tgt * 16 + jj];
      const float ig = sigf(pre[0]);
      const float fg = sigf(pre[1]);
      const float gg = tanhff(pre[2]);
      const float og = sigf(pre[3]);
      cst = fmaf(fg, cst, ig * gg);
      const float h = og * tanhff(cst);
      hbuf[cur ^ 1][bd][jj] = h;
      out3[((size_t)(b0 + bd) * TL + tt) * 32 + dir * 16 + jj] = h;
    }
    if ((t & 7) == 7 && t + 1 < TL){
      #pragma unroll
      for (int i = 0; i < 4; ++i)
        *(float4*)&xsb[pbuf ^ 1][bld][l32 * 4 + i * 128] = pf[i];
      pbuf ^= 1;
    }
    __syncthreads();
  }
}

// ---------------- fp32 GEMM: X[m][n] = sum_k A[m][k]*W[n][k] + ba[n]+bb[n]
// BM=BN=128, BK=16, 256 thr, 8x8/thread, next-tile register prefetch.
template<bool DIRSPLIT>
__global__ __launch_bounds__(256, 2) void gemm_nt_kernel(
    const float* __restrict__ A, const float* __restrict__ W,
    const float* __restrict__ ba, const float* __restrict__ bb,
    float* __restrict__ X, int M, int N, int K)
{
  __shared__ __align__(16) float As[16 * 132];
  __shared__ __align__(16) float Bs[16 * 132];
  const int tid = threadIdx.x;
  const int m0 = blockIdx.x * 128, n0 = blockIdx.y * 128;
  const int lm = tid >> 1, lk = (tid & 1) << 3;
  const float* Ap = A + (size_t)(m0 + lm) * K + lk;
  const float* Wp = W + (size_t)(n0 + lm) * K + lk;
  float4 pa0 = *(const float4*)Ap,       pa1 = *(const float4*)(Ap + 4);
  float4 pb0 = *(const float4*)Wp,       pb1 = *(const float4*)(Wp + 4);
  const int tr = tid >> 4, tc = tid & 15;
  float acc[8][8];
  #pragma unroll
  for (int i = 0; i < 8; ++i)
    #pragma unroll
    for (int jj = 0; jj < 8; ++jj) acc[i][jj] = 0.0f;

  const int KT = K >> 4;
  for (int kt = 0; kt < KT; ++kt){
    __syncthreads();
    #pragma unroll
    for (int i = 0; i < 4; ++i){
      As[(lk + i) * 132 + lm]     = (&pa0.x)[i];
      As[(lk + 4 + i) * 132 + lm] = (&pa1.x)[i];
      Bs[(lk + i) * 132 + lm]     = (&pb0.x)[i];
      Bs[(lk + 4 + i) * 132 + lm] = (&pb1.x)[i];
    }
    __syncthreads();
    if (kt + 1 < KT){
      Ap += 16; Wp += 16;
      pa0 = *(const float4*)Ap; pa1 = *(const float4*)(Ap + 4);
      pb0 = *(const float4*)Wp; pb1 = *(const float4*)(Wp + 4);
    }
    const float4* As4 = (const float4*)As;
    const float4* Bs4 = (const float4*)Bs;
    #pragma unroll
    for (int kk = 0; kk < 16; ++kk){
      const float4 a0 = As4[kk * 33 + tr * 2], a1 = As4[kk * 33 + tr * 2 + 1];
      const float4 b0 = Bs4[kk * 33 + tc * 2], b1 = Bs4[kk * 33 + tc * 2 + 1];
      const float av[8] = {a0.x, a0.y, a0.z, a0.w, a1.x, a1.y, a1.z, a1.w};
      const float bv[8] = {b0.x, b0.y, b0.z, b0.w, b1.x, b1.y, b1.z, b1.w};
      #pragma unroll
      for (int i = 0; i < 8; ++i)
        #pragma unroll
        for (int jj = 0; jj < 8; ++jj)
          acc[i][jj] = fmaf(av[i], bv[jj], acc[i][jj]);
    }
  }
  float bias[8];
  #pragma unroll
  for (int jj = 0; jj < 8; ++jj){
    const int n = n0 + tc * 8 + jj;
    bias[jj] = ba[n] + bb[n];
  }
  #pragma unroll
  for (int i = 0; i < 8; ++i){
    const int m = m0 + tr * 8 + i;
    float v[8];
    #pragma unroll
    for (int jj = 0; jj < 8; ++jj) v[jj] = acc[i][jj] + bias[jj];
    if (!DIRSPLIT){
      float4* dst = (float4*)(X + (size_t)m * N + n0 + tc * 8);
      dst[0] = make_float4(v[0], v[1], v[2], v[3]);
      dst[1] = make_float4(v[4], v[5], v[6], v[7]);
    } else {
      const int dp = tc >> 3;           // n0==0, n = tc*8
      const int nc = (tc & 7) * 8;
      float4* dst = (float4*)(X + (size_t)dp * ((size_t)M * 64) + (size_t)m * 64 + nc);
      dst[0] = make_float4(v[0], v[1], v[2], v[3]);
      dst[1] = make_float4(v[4], v[5], v[6], v[7]);
    }
  }
}

// ---------------- mean over T + MLP head, one WG per batch
__global__ __launch_bounds__(256) void head_kernel(
    const float* __restrict__ out3,
    const float* __restrict__ hW1, const float* __restrict__ hb1,
    const float* __restrict__ hW2, const float* __restrict__ hb2,
    const float* __restrict__ hW3, const float* __restrict__ hb3,
    float* __restrict__ out)
{
  __shared__ float part[256];
  __shared__ float m[32];
  __shared__ float h1[64];
  __shared__ float h2[16];
  const int tid = threadIdx.x;
  const int b = blockIdx.x;
  const int c = tid & 31, ts = tid >> 5;
  float s = 0.0f;
  const float* p = out3 + ((size_t)b * TL + ts * 256) * 32 + c;
  for (int i = 0; i < 256; ++i) s += p[i * 32];
  part[tid] = s;
  __syncthreads();
  if (tid < 32){
    float a = 0.0f;
    #pragma unroll
    for (int r = 0; r < 8; ++r) a += part[r * 32 + tid];
    m[tid] = a * (1.0f / 2048.0f);
  }
  __syncthreads();
  if (tid < 64){
    float a = hb1[tid];
    #pragma unroll
    for (int k = 0; k < 32; ++k) a = fmaf(m[k], hW1[tid * 32 + k], a);
    h1[tid] = fmaxf(a, 0.0f);
  }
  __syncthreads();
  if (tid < 16){
    float a = hb2[tid];
    #pragma unroll
    for (int k = 0; k < 64; ++k) a = fmaf(h1[k], hW2[tid * 64 + k], a);
    h2[tid] = fmaxf(a, 0.0f);
  }
  __syncthreads();
  if (tid < 20){
    float a = hb3[tid];
    #pragma unroll
    for (int k = 0; k < 16; ++k) a = fmaf(h2[k], hW3[tid * 16 + k], a);
    out[b * 20 + tid] = a;
  }
}

extern "C" void kernel_launch(void* const* d_in, const int* in_sizes, int n_in,
                              void* d_out, int out_size, void* d_ws, size_t ws_size,
                              hipStream_t stream) {
  (void)in_sizes; (void)n_in; (void)out_size;
  const float* x    = (const float*)d_in[0];
  const float* Wih1 = (const float*)d_in[1];
  const float* Whh1 = (const float*)d_in[2];
  const float* bih1 = (const float*)d_in[3];
  const float* bhh1 = (const float*)d_in[4];
  const float* Wih2 = (const float*)d_in[5];
  const float* Whh2 = (const float*)d_in[6];
  const float* bih2 = (const float*)d_in[7];
  const float* bhh2 = (const float*)d_in[8];
  const float* Wih3 = (const float*)d_in[9];
  const float* Whh3 = (const float*)d_in[10];
  const float* bih3 = (const float*)d_in[11];
  const float* bhh3 = (const float*)d_in[12];
  const float* hW1  = (const float*)d_in[13];
  const float* hb1  = (const float*)d_in[14];
  const float* hW2  = (const float*)d_in[15];
  const float* hb2  = (const float*)d_in[16];
  const float* hW3  = (const float*)d_in[17];
  const float* hb3  = (const float*)d_in[18];

  float* ws = (float*)d_ws;

  // Per-batch workspace (floats): out1 = T*256, xs2 = T*256 (per dir), out2 = T*128.
  // xs3 (T*128) + out3 (T*32) reuse out1's region after it dies.
  // Plan A (BC==256 only): both-dir xs2 resident -> one extra T*256 per batch.
  const size_t PB_B = (size_t)TL * (256 + 256 + 128) * 4;  // plan-B bytes/batch
  const bool planA = ws_size >= (size_t)256 * TL * (256 + 512 + 128) * 4;
  int BC = 2;
  for (int c = 256; c >= 2; c >>= 1){
    if ((size_t)c * PB_B <= ws_size){ BC = c; break; }
  }
  if (planA) BC = 256;

  const size_t N_OUT1 = (size_t)BC * TL * 256;
  const size_t N_XS2D = (size_t)BC * TL * 256;
  const int M = BC * TL;

  float* out1 = ws;
  float* xs2  = ws + N_OUT1;
  float* out2 = xs2 + (planA ? 2 : 1) * N_XS2D;
  float* xs3  = ws;                          // reuses out1 (dead after L2 gemms)
  float* out3 = ws + (size_t)BC * TL * 128;  // after xs3, still inside old out1

  for (int cb = 0; cb < 256; cb += BC){
    scan1_kernel<<<dim3(BC / 2, 2), dim3(512), 0, stream>>>(
        x + (size_t)cb * TL * 2, Wih1, Whh1, bih1, bhh1, out1);

    if (planA){
      for (int dir = 0; dir < 2; ++dir)
        gemm_nt_kernel<false><<<dim3(M / 128, 2), dim3(256), 0, stream>>>(
            out1, Wih2 + dir * 65536, bih2 + dir * 256, bhh2 + dir * 256,
            xs2 + (size_t)dir * N_XS2D, M, 256, 256);
      scan2_kernel<<<dim3(BC, 2), dim3(512), 0, stream>>>(xs2, N_XS2D, 0, Whh2, out2);
    } else {
      for (int dir = 0; dir < 2; ++dir){
        gemm_nt_kernel<false><<<dim3(M / 128, 2), dim3(256), 0, stream>>>(
            out1, Wih2 + dir * 65536, bih2 + dir * 256, bhh2 + dir * 256,
            xs2, M, 256, 256);
        scan2_kernel<<<dim3(BC, 1), dim3(512), 0, stream>>>(xs2, 0, dir, Whh2, out2);
      }
    }

    gemm_nt_kernel<true><<<dim3(M / 128, 1), dim3(256), 0, stream>>>(
        out2, Wih3, bih3, bhh3, xs3, M, 128, 128);
    scan3_kernel<<<dim3(BC / 2, 2), dim3(64), 0, stream>>>(
        xs3, (size_t)M * 64, Whh3, out3);
    head_kernel<<<dim3(BC), dim3(256), 0, stream>>>(
        out3, hW1, hb1, hW2, hb2, hW3, hb3, (float*)d_out + (size_t)cb * 20);
  }
}

// Round 3
// 16272.285 us; speedup vs baseline: 2.9375x; 2.9375x over previous
//
#include <hip/hip_runtime.h>

#define TL 2048

__device__ __forceinline__ float sigf(float x){ return __builtin_amdgcn_rcpf(1.0f + __expf(-x)); }
__device__ __forceinline__ float tanhff(float x){ return fmaf(2.0f, sigf(2.0f*x), -1.0f); }

// butterfly-add: quad_perm xor1 (0xB1), xor2 (0x4E), ds_swizzle xor4
template<int CTRL>
__device__ __forceinline__ float dpp_xadd(float v){
  int s = __builtin_amdgcn_update_dpp(0, __float_as_int(v), CTRL, 0xF, 0xF, true);
  return v + __int_as_float(s);
}
__device__ __forceinline__ float swz4_add(float v){
  int s = __builtin_amdgcn_ds_swizzle(__float_as_int(v), 0x101F);
  return v + __int_as_float(s);
}
__device__ __forceinline__ float bperm(float v, int srclane){
  return __int_as_float(__builtin_amdgcn_ds_bpermute(srclane << 2, __float_as_int(v)));
}
__device__ __forceinline__ unsigned short f2bf(float f){   // RNE fp32->bf16
  unsigned int u = __float_as_uint(f);
  u += 0x7fffu + ((u >> 16) & 1u);
  return (unsigned short)(u >> 16);
}
__device__ __forceinline__ float dot4(float4 a, float4 b, float acc){
  acc = fmaf(a.x, b.x, acc); acc = fmaf(a.y, b.y, acc);
  acc = fmaf(a.z, b.z, acc); acc = fmaf(a.w, b.w, acc);
  return acc;
}

// Pipelined uber-kernel: blockIdx in [0,nL1) = L1 scan of chunk cL1,
// [nL1,nL1+nL2) = L2 scan (fused Wih2 proj) of chunk cL2,
// rest = L3 scan (fused Wih3 proj + T-mean) of chunk cL3. BC=32 batches/chunk.
__global__ __launch_bounds__(512, 2) void mega_kernel(
    int nL1, int cL1, int nL2, int cL2, int nL3, int cL3,
    const float* __restrict__ x,
    const float* __restrict__ Wih1, const float* __restrict__ Whh1,
    const float* __restrict__ bih1, const float* __restrict__ bhh1,
    const float* __restrict__ Wih2, const float* __restrict__ Whh2,
    const float* __restrict__ bih2, const float* __restrict__ bhh2,
    const float* __restrict__ Wih3, const float* __restrict__ Whh3,
    const float* __restrict__ bih3, const float* __restrict__ bhh3,
    unsigned short* __restrict__ h1r0, unsigned short* __restrict__ h1r1,
    float* __restrict__ o2r0, float* __restrict__ o2r1,
    float* __restrict__ sums)
{
  __shared__ __align__(16) unsigned char smem[34816];
  const int tid = threadIdx.x;
  const int bid = blockIdx.x;

  if (bid < nL1){
    // ================= L1: H=128, D=2 folded. WG = one (b,dir) chain. =====
    const int b = bid & 31, dir = bid >> 5;
    unsigned short* h1o = (cL1 & 1) ? h1r1 : h1r0;
    const int kc = tid & 3, u = tid >> 2;          // kc-split K into 4x32

    // Whh fragments, pre-rotated k-blocks so LDS reads are conflict-free
    float4 w[4][8];
    const float* Wh = Whh1 + dir * 65536;
    #pragma unroll
    for (int g = 0; g < 4; ++g){
      const float* row = Wh + (g * 128 + u) * 128 + kc * 32;
      #pragma unroll
      for (int q = 0; q < 8; ++q){
        const int ro = (q + 2 * kc) & 7;
        w[g][q] = *(const float4*)(row + ro * 4);
      }
    }
    float xwA[4], xwB[4], bs[4];
    #pragma unroll
    for (int g = 0; g < 4; ++g){
      const int r = g * 128 + u;
      xwA[g] = Wih1[dir * 1024 + r * 2];
      xwB[g] = Wih1[dir * 1024 + r * 2 + 1];
      bs[g]  = bih1[dir * 512 + r] + bhh1[dir * 512 + r];
    }
    float* xlds = (float*)smem;                  // 4096 f = 16KB (full x row)
    float* hbuf = (float*)(smem + 16384);        // 2 x 128 f
    {
      const float* xb = x + (size_t)(cL1 * 32 + b) * (TL * 2);
      for (int idx = tid; idx < TL * 2; idx += 512) xlds[idx] = xb[idx];
    }
    if (tid < 128){ hbuf[tid] = 0.0f; hbuf[128 + tid] = 0.0f; }
    __syncthreads();

    float cst = 0.0f;
    for (int t = 0; t < TL; ++t){
      const int tt  = dir ? (TL - 1 - t) : t;
      const int cur = t & 1;
      const float4* hp = (const float4*)(hbuf + cur * 128) + kc * 8;
      float a0 = 0.f, a1 = 0.f, a2 = 0.f, a3 = 0.f;
      #pragma unroll
      for (int q = 0; q < 8; ++q){
        const float4 hv = hp[(q + 2 * kc) & 7];
        a0 = dot4(w[0][q], hv, a0);
        a1 = dot4(w[1][q], hv, a1);
        a2 = dot4(w[2][q], hv, a2);
        a3 = dot4(w[3][q], hv, a3);
      }
      a0 = dpp_xadd<0x4E>(dpp_xadd<0xB1>(a0));
      a1 = dpp_xadd<0x4E>(dpp_xadd<0xB1>(a1));
      a2 = dpp_xadd<0x4E>(dpp_xadd<0xB1>(a2));
      a3 = dpp_xadd<0x4E>(dpp_xadd<0xB1>(a3));
      if (kc == 0){
        const float x0 = xlds[tt * 2], x1 = xlds[tt * 2 + 1];
        const float p0 = a0 + fmaf(xwA[0], x0, fmaf(xwB[0], x1, bs[0]));
        const float p1 = a1 + fmaf(xwA[1], x0, fmaf(xwB[1], x1, bs[1]));
        const float p2 = a2 + fmaf(xwA[2], x0, fmaf(xwB[2], x1, bs[2]));
        const float p3 = a3 + fmaf(xwA[3], x0, fmaf(xwB[3], x1, bs[3]));
        const float ig = sigf(p0), fg = sigf(p1), gg = tanhff(p2), og = sigf(p3);
        cst = fmaf(fg, cst, ig * gg);
        const float h = og * tanhff(cst);
        hbuf[(cur ^ 1) * 128 + u] = h;
        h1o[((size_t)b * TL + tt) * 256 + dir * 128 + u] = f2bf(h);
      }
      __syncthreads();
    }

  } else if (bid < nL1 + nL2){
    // ================= L2: H=64, fused 256-wide input projection. =========
    const int i2 = bid - nL1;
    const int b = i2 & 31, dir = i2 >> 5;
    const unsigned short* h1i = ((cL2 & 1) ? h1r1 : h1r0) + (size_t)b * TL * 256;
    float* o2o = (cL2 & 1) ? o2r1 : o2r0;
    const int kc = tid & 7, u = tid >> 3;          // kc-split: proj K 8x32, rec K 8x8

    float4 wp[4][8], wr[4][2];
    const float* WP = Wih2 + dir * 65536;          // (256,256)
    const float* WR = Whh2 + dir * 16384;          // (256,64)
    float bs[4];
    #pragma unroll
    for (int g = 0; g < 4; ++g){
      const int r = g * 64 + u;
      #pragma unroll
      for (int q = 0; q < 4; ++q){                 // pre-rotated 8-elem blocks
        const int ro = (q + kc) & 3;
        wp[g][2 * q]     = *(const float4*)(WP + r * 256 + kc * 32 + ro * 8);
        wp[g][2 * q + 1] = *(const float4*)(WP + r * 256 + kc * 32 + ro * 8 + 4);
      }
      wr[g][0] = *(const float4*)(WR + r * 64 + kc * 8);
      wr[g][1] = *(const float4*)(WR + r * 64 + kc * 8 + 4);
      bs[g] = bih2[dir * 256 + r] + bhh2[dir * 256 + r];
    }
    unsigned short* h1c = (unsigned short*)smem;   // 2 x 8steps x 256 bf16 = 8KB
    float* h2b = (float*)(smem + 8192);            // 2 x 64 f
    {
      const int ttS0 = dir ? (TL - 8) : 0;
      uint2 v = *((const uint2*)(h1i + (size_t)ttS0 * 256) + tid);
      *((uint2*)h1c + tid) = v;
    }
    if (tid < 64){ h2b[tid] = 0.0f; h2b[64 + tid] = 0.0f; }
    __syncthreads();

    float cst = 0.0f; int pbuf = 0;
    uint2 pf = make_uint2(0u, 0u);
    for (int t = 0; t < TL; ++t){
      const int tt   = dir ? (TL - 1 - t) : t;
      const int cur  = t & 1;
      const int slot = dir ? (7 - (t & 7)) : (t & 7);
      if ((t & 7) == 0 && t + 8 < TL){
        const int c1  = (t >> 3) + 1;
        const int ttS = dir ? (TL - 8 * (c1 + 1)) : 8 * c1;
        pf = *((const uint2*)(h1i + (size_t)ttS * 256) + tid);
      }
      const unsigned short* hrow = h1c + pbuf * 2048 + slot * 256;
      const uint4* hp = (const uint4*)(hrow + kc * 32);
      float a0 = 0.f, a1 = 0.f, a2 = 0.f, a3 = 0.f;
      #pragma unroll
      for (int q = 0; q < 4; ++q){
        const uint4 raw = hp[(q + kc) & 3];
        const float f0 = __uint_as_float(raw.x << 16);
        const float f1 = __uint_as_float(raw.x & 0xffff0000u);
        const float f2 = __uint_as_float(raw.y << 16);
        const float f3 = __uint_as_float(raw.y & 0xffff0000u);
        const float f4 = __uint_as_float(raw.z << 16);
        const float f5 = __uint_as_float(raw.z & 0xffff0000u);
        const float f6 = __uint_as_float(raw.w << 16);
        const float f7 = __uint_as_float(raw.w & 0xffff0000u);
        #pragma unroll
        for (int g = 0; g < 4; ++g){
          float* ag = (g == 0) ? &a0 : (g == 1) ? &a1 : (g == 2) ? &a2 : &a3;
          float v = *ag;
          const float4 pA = wp[g][2 * q], pB = wp[g][2 * q + 1];
          v = fmaf(pA.x, f0, v); v = fmaf(pA.y, f1, v);
          v = fmaf(pA.z, f2, v); v = fmaf(pA.w, f3, v);
          v = fmaf(pB.x, f4, v); v = fmaf(pB.y, f5, v);
          v = fmaf(pB.z, f6, v); v = fmaf(pB.w, f7, v);
          *ag = v;
        }
      }
      const float4* h2p = (const float4*)(h2b + cur * 64) + kc * 2;
      const float4 hA = h2p[0], hB = h2p[1];
      a0 = dot4(wr[0][0], hA, a0); a0 = dot4(wr[0][1], hB, a0);
      a1 = dot4(wr[1][0], hA, a1); a1 = dot4(wr[1][1], hB, a1);
      a2 = dot4(wr[2][0], hA, a2); a2 = dot4(wr[2][1], hB, a2);
      a3 = dot4(wr[3][0], hA, a3); a3 = dot4(wr[3][1], hB, a3);
      a0 = swz4_add(dpp_xadd<0x4E>(dpp_xadd<0xB1>(a0)));
      a1 = swz4_add(dpp_xadd<0x4E>(dpp_xadd<0xB1>(a1)));
      a2 = swz4_add(dpp_xadd<0x4E>(dpp_xadd<0xB1>(a2)));
      a3 = swz4_add(dpp_xadd<0x4E>(dpp_xadd<0xB1>(a3)));
      if (kc == 0){
        const float ig = sigf(a0 + bs[0]);
        const float fg = sigf(a1 + bs[1]);
        const float gg = tanhff(a2 + bs[2]);
        const float og = sigf(a3 + bs[3]);
        cst = fmaf(fg, cst, ig * gg);
        const float h = og * tanhff(cst);
        h2b[(cur ^ 1) * 64 + u] = h;
        o2o[((size_t)b * TL + tt) * 128 + dir * 64 + u] = h;
      }
      if ((t & 7) == 7 && t + 1 < TL){
        *((uint2*)(h1c + (pbuf ^ 1) * 2048) + tid) = pf;
        pbuf ^= 1;
      }
      __syncthreads();
    }

  } else {
    // ================= L3: H=16, fused 128-wide proj + T-mean accumulate. =
    // WG = 4 chains (same dir), 128 thr/chain: u(16) x gate(4) x kc(2).
    const int i3 = bid - nL1 - nL2;
    const int dir = i3 & 1, q4 = i3 >> 1;
    const int grp = tid >> 7, lt = tid & 127;
    const int b = q4 * 4 + grp;
    const int u = lt >> 3, j = lt & 7, gt = j >> 1, kc = j & 1;
    const float* o2i = ((cL3 & 1) ? o2r1 : o2r0) + (size_t)b * TL * 128;

    const float* WP = Wih3 + dir * 8192;           // (64,128)
    const float* WR = Whh3 + dir * 1024;           // (64,16)
    const int r = gt * 16 + u;
    float4 wp[16], wr0, wr1;
    #pragma unroll
    for (int q = 0; q < 16; ++q) wp[q] = *(const float4*)(WP + r * 128 + kc * 64 + q * 4);
    wr0 = *(const float4*)(WR + r * 16 + kc * 8);
    wr1 = *(const float4*)(WR + r * 16 + kc * 8 + 4);
    const float bsv = bih3[dir * 64 + r] + bhh3[dir * 64 + r];
    const int lane = tid & 63;
    const int ubase = lane & ~7;
    const float bI = bperm(bsv, ubase + 0), bF = bperm(bsv, ubase + 2);
    const float bG = bperm(bsv, ubase + 4), bO = bperm(bsv, ubase + 6);

    float* o2c = (float*)smem + grp * 2048;        // 2 bufs x 8 x 128 f per grp
    float* h3b = (float*)(smem + 32768) + grp * 32;
    if (lt < 32) h3b[lt] = 0.0f;
    {
      const int ttS0 = dir ? (TL - 8) : 0;
      const float4 a = *(const float4*)(o2i + (size_t)ttS0 * 128 + lt * 8);
      const float4 c = *(const float4*)(o2i + (size_t)ttS0 * 128 + lt * 8 + 4);
      ((float4*)o2c)[lt * 2] = a; ((float4*)o2c)[lt * 2 + 1] = c;
    }
    __syncthreads();

    float cst = 0.0f, msum = 0.0f; int pbuf = 0;
    float4 pf0 = make_float4(0,0,0,0), pf1 = make_float4(0,0,0,0);
    for (int t = 0; t < TL; ++t){
      const int tt   = dir ? (TL - 1 - t) : t;
      const int cur  = t & 1;
      const int slot = dir ? (7 - (t & 7)) : (t & 7);
      if ((t & 7) == 0 && t + 8 < TL){
        const int c1  = (t >> 3) + 1;
        const int ttS = dir ? (TL - 8 * (c1 + 1)) : 8 * c1;
        pf0 = *(const float4*)(o2i + (size_t)ttS * 128 + lt * 8);
        pf1 = *(const float4*)(o2i + (size_t)ttS * 128 + lt * 8 + 4);
      }
      const float4* hrow = (const float4*)(o2c + pbuf * 1024 + slot * 128 + kc * 64);
      float acc = 0.0f;
      #pragma unroll
      for (int q = 0; q < 16; ++q) acc = dot4(wp[q], hrow[q], acc);
      const float4* h3p = (const float4*)(h3b + cur * 16 + kc * 8);
      acc = dot4(wr0, h3p[0], acc);
      acc = dot4(wr1, h3p[1], acc);
      acc = dpp_xadd<0xB1>(acc);                   // reduce kc pair
      const float gI = bperm(acc, ubase + 0), gF = bperm(acc, ubase + 2);
      const float gG = bperm(acc, ubase + 4), gO = bperm(acc, ubase + 6);
      if (j == 0){
        const float ig = sigf(gI + bI), fg = sigf(gF + bF);
        const float gg = tanhff(gG + bG), og = sigf(gO + bO);
        cst = fmaf(fg, cst, ig * gg);
        const float h = og * tanhff(cst);
        h3b[(cur ^ 1) * 16 + u] = h;
        msum += h;
      }
      if ((t & 7) == 7 && t + 1 < TL){
        ((float4*)(o2c + (pbuf ^ 1) * 1024))[lt * 2] = pf0;
        ((float4*)(o2c + (pbuf ^ 1) * 1024))[lt * 2 + 1] = pf1;
        pbuf ^= 1;
      }
      __syncthreads();
    }
    if (j == 0) sums[(size_t)(cL3 * 32 + b) * 32 + dir * 16 + u] = msum;
  }
}

// ---------------- head: mean (already summed) + MLP, one 64-thr WG per batch
__global__ __launch_bounds__(64) void head_kernel(
    const float* __restrict__ sums,
    const float* __restrict__ hW1, const float* __restrict__ hb1,
    const float* __restrict__ hW2, const float* __restrict__ hb2,
    const float* __restrict__ hW3, const float* __restrict__ hb3,
    float* __restrict__ out)
{
  __shared__ float m[32], h1s[64], h2s[16];
  const int tid = threadIdx.x, b = blockIdx.x;
  if (tid < 32) m[tid] = sums[b * 32 + tid] * (1.0f / 2048.0f);
  __syncthreads();
  {
    float a = hb1[tid];
    #pragma unroll
    for (int k = 0; k < 32; ++k) a = fmaf(m[k], hW1[tid * 32 + k], a);
    h1s[tid] = fmaxf(a, 0.0f);
  }
  __syncthreads();
  if (tid < 16){
    float a = hb2[tid];
    #pragma unroll
    for (int k = 0; k < 64; ++k) a = fmaf(h1s[k], hW2[tid * 64 + k], a);
    h2s[tid] = fmaxf(a, 0.0f);
  }
  __syncthreads();
  if (tid < 20){
    float a = hb3[tid];
    #pragma unroll
    for (int k = 0; k < 16; ++k) a = fmaf(h2s[k], hW3[tid * 16 + k], a);
    out[b * 20 + tid] = a;
  }
}

extern "C" void kernel_launch(void* const* d_in, const int* in_sizes, int n_in,
                              void* d_out, int out_size, void* d_ws, size_t ws_size,
                              hipStream_t stream) {
  (void)in_sizes; (void)n_in; (void)out_size; (void)ws_size;
  const float* x    = (const float*)d_in[0];
  const float* Wih1 = (const float*)d_in[1];
  const float* Whh1 = (const float*)d_in[2];
  const float* bih1 = (const float*)d_in[3];
  const float* bhh1 = (const float*)d_in[4];
  const float* Wih2 = (const float*)d_in[5];
  const float* Whh2 = (const float*)d_in[6];
  const float* bih2 = (const float*)d_in[7];
  const float* bhh2 = (const float*)d_in[8];
  const float* Wih3 = (const float*)d_in[9];
  const float* Whh3 = (const float*)d_in[10];
  const float* bih3 = (const float*)d_in[11];
  const float* bhh3 = (const float*)d_in[12];
  const float* hW1  = (const float*)d_in[13];
  const float* hb1  = (const float*)d_in[14];
  const float* hW2  = (const float*)d_in[15];
  const float* hb2  = (const float*)d_in[16];
  const float* hW3  = (const float*)d_in[17];
  const float* hb3  = (const float*)d_in[18];

  // Workspace map (ws_size >= 167.8MB proven by round-2's BC=32 run; need 134.25MB):
  // [0,32M):   h1 ring0 bf16 (32,2048,256)   [32M,64M): h1 ring1
  // [64M,96M): out2 ring0 f32 (32,2048,128)  [96M,128M): out2 ring1
  // [128M,+32K): per-(b,dir,unit) T-sums f32 (256,32)
  const size_t H1E = (size_t)32 * TL * 256;   // ushorts per h1 ring buffer
  unsigned short* h1r0 = (unsigned short*)d_ws;
  unsigned short* h1r1 = h1r0 + H1E;
  float* o2r0 = (float*)((unsigned char*)d_ws + 67108864u);
  float* o2r1 = o2r0 + (size_t)32 * TL * 128;
  float* sums = (float*)((unsigned char*)d_ws + 134217728u);

  // Software pipeline over 8 chunks of 32 batches: launch k runs
  // L1(chunk k) || L2(chunk k-1) || L3(chunk k-2).
  for (int k = 0; k < 10; ++k){
    const int nL1 = (k < 8) ? 64 : 0;
    const int nL2 = (k >= 1 && k < 9) ? 64 : 0;
    const int nL3 = (k >= 2) ? 16 : 0;
    mega_kernel<<<dim3(nL1 + nL2 + nL3), dim3(512), 0, stream>>>(
        nL1, k, nL2, k - 1, nL3, k - 2,
        x, Wih1, Whh1, bih1, bhh1, Wih2, Whh2, bih2, bhh2,
        Wih3, Whh3, bih3, bhh3, h1r0, h1r1, o2r0, o2r1, sums);
  }
  head_kernel<<<dim3(256), dim3(64), 0, stream>>>(
      sums, hW1, hb1, hW2, hb2, hW3, hb3, (float*)d_out);
}

// Round 4
// 10047.502 us; speedup vs baseline: 4.7574x; 1.6195x over previous
//
#include <hip/hip_runtime.h>

#define TL 2048

typedef __attribute__((ext_vector_type(8))) short bfx8;
typedef __attribute__((ext_vector_type(4))) float fx4;

__device__ __forceinline__ float sigf(float x){ return __builtin_amdgcn_rcpf(1.0f + __expf(-x)); }
__device__ __forceinline__ float tanhff(float x){ return fmaf(2.0f, sigf(2.0f*x), -1.0f); }

template<int CTRL>
__device__ __forceinline__ float dpp_xadd(float v){
  int s = __builtin_amdgcn_update_dpp(0, __float_as_int(v), CTRL, 0xF, 0xF, true);
  return v + __int_as_float(s);
}
__device__ __forceinline__ float swz4_add(float v){
  int s = __builtin_amdgcn_ds_swizzle(__float_as_int(v), 0x101F);
  return v + __int_as_float(s);
}
__device__ __forceinline__ float bperm(float v, int srclane){
  return __int_as_float(__builtin_amdgcn_ds_bpermute(srclane << 2, __float_as_int(v)));
}
__device__ __forceinline__ unsigned short f2bf(float f){   // RNE fp32->bf16
  unsigned int u = __float_as_uint(f);
  u += 0x7fffu + ((u >> 16) & 1u);
  return (unsigned short)(u >> 16);
}
__device__ __forceinline__ float dot4(float4 a, float4 b, float acc){
  acc = fmaf(a.x, b.x, acc); acc = fmaf(a.y, b.y, acc);
  acc = fmaf(a.z, b.z, acc); acc = fmaf(a.w, b.w, acc);
  return acc;
}
// LDS-only barrier: do NOT drain vmcnt (global h-stores stay in flight).
__device__ __forceinline__ void barrier_lgkm(){
  asm volatile("s_waitcnt lgkmcnt(0)\ns_barrier" ::: "memory");
}
__device__ __forceinline__ bfx8 pack8(const float* p){
  bfx8 r;
  #pragma unroll
  for (int i = 0; i < 8; ++i) r[i] = (short)f2bf(p[i]);
  return r;
}

// Pipelined uber-kernel, BC up to 48 batches/chunk:
//   blockIdx [0,nL1)            : L1 scan (fp32 VALU, D=2 folded), h1 out bf16
//   blockIdx [nL1,nL1+nL2)      : L2 scan, Wih2 proj via MFMA 16-step lookahead
//   blockIdx [nL1+nL2, +nL3)    : L3 scan, Wih3 proj via MFMA + T-mean accumulate
__global__ __launch_bounds__(512, 2) void mega_kernel(
    int nL1, int nL2, int nL3, int cb1, int cb2, int cb3, int p1, int p2, int p3,
    const float* __restrict__ x,
    const float* __restrict__ Wih1, const float* __restrict__ Whh1,
    const float* __restrict__ bih1, const float* __restrict__ bhh1,
    const float* __restrict__ Wih2, const float* __restrict__ Whh2,
    const float* __restrict__ bih2, const float* __restrict__ bhh2,
    const float* __restrict__ Wih3, const float* __restrict__ Whh3,
    const float* __restrict__ bih3, const float* __restrict__ bhh3,
    unsigned short* __restrict__ h1r0, unsigned short* __restrict__ h1r1,
    unsigned short* __restrict__ o2r0, unsigned short* __restrict__ o2r1,
    float* __restrict__ sums)
{
  __shared__ __align__(16) unsigned char smem[34816];
  const int tid  = threadIdx.x;
  const int bid  = blockIdx.x;
  const int lane = tid & 63;
  const int wv   = tid >> 6;

  if (bid < nL1){
    // ================= L1: H=128, D=2 folded. WG = one (b,dir) chain. ======
    const int bloc = bid >> 1, dir = bid & 1;
    unsigned short* h1o = p1 ? h1r1 : h1r0;
    const int kc = tid & 3, u = tid >> 2;

    float4 w[4][8];
    const float* Wh = Whh1 + dir * 65536;
    #pragma unroll
    for (int g = 0; g < 4; ++g){
      const float* row = Wh + (g * 128 + u) * 128 + kc * 32;
      #pragma unroll
      for (int q = 0; q < 8; ++q){
        const int ro = (q + 2 * kc) & 7;
        w[g][q] = *(const float4*)(row + ro * 4);
      }
    }
    float xwA[4], xwB[4], bs[4];
    #pragma unroll
    for (int g = 0; g < 4; ++g){
      const int r = g * 128 + u;
      xwA[g] = Wih1[dir * 1024 + r * 2];
      xwB[g] = Wih1[dir * 1024 + r * 2 + 1];
      bs[g]  = bih1[dir * 512 + r] + bhh1[dir * 512 + r];
    }
    float* xlds = (float*)smem;                  // 4096 f (full x row)
    float* hbuf = (float*)(smem + 16384);        // 2 x 128 f
    {
      const float* xb = x + (size_t)(cb1 + bloc) * (TL * 2);
      for (int idx = tid; idx < TL * 2; idx += 512) xlds[idx] = xb[idx];
    }
    if (tid < 128){ hbuf[tid] = 0.0f; hbuf[128 + tid] = 0.0f; }
    __syncthreads();

    float cst = 0.0f;
    for (int t = 0; t < TL; ++t){
      const int tt  = dir ? (TL - 1 - t) : t;
      const int cur = t & 1;
      const float4* hp = (const float4*)(hbuf + cur * 128) + kc * 8;
      float a0 = 0.f, a1 = 0.f, a2 = 0.f, a3 = 0.f;
      #pragma unroll
      for (int q = 0; q < 8; ++q){
        const float4 hv = hp[(q + 2 * kc) & 7];
        a0 = dot4(w[0][q], hv, a0);
        a1 = dot4(w[1][q], hv, a1);
        a2 = dot4(w[2][q], hv, a2);
        a3 = dot4(w[3][q], hv, a3);
      }
      a0 = dpp_xadd<0x4E>(dpp_xadd<0xB1>(a0));
      a1 = dpp_xadd<0x4E>(dpp_xadd<0xB1>(a1));
      a2 = dpp_xadd<0x4E>(dpp_xadd<0xB1>(a2));
      a3 = dpp_xadd<0x4E>(dpp_xadd<0xB1>(a3));
      if (kc == 0){
        const float x0 = xlds[tt * 2], x1 = xlds[tt * 2 + 1];
        const float p0 = a0 + fmaf(xwA[0], x0, fmaf(xwB[0], x1, bs[0]));
        const float p1 = a1 + fmaf(xwA[1], x0, fmaf(xwB[1], x1, bs[1]));
        const float p2 = a2 + fmaf(xwA[2], x0, fmaf(xwB[2], x1, bs[2]));
        const float p3 = a3 + fmaf(xwA[3], x0, fmaf(xwB[3], x1, bs[3]));
        const float ig = sigf(p0), fg = sigf(p1), gg = tanhff(p2), og = sigf(p3);
        cst = fmaf(fg, cst, ig * gg);
        const float h = og * tanhff(cst);
        hbuf[(cur ^ 1) * 128 + u] = h;
        h1o[((size_t)bloc * TL + tt) * 256 + dir * 128 + u] = f2bf(h);
      }
      barrier_lgkm();
    }

  } else if (bid < nL1 + nL2){
    // ================= L2: H=64; proj (K=256) via MFMA lookahead. ==========
    const int i2 = bid - nL1;
    const int bloc = i2 >> 1, dir = i2 & 1;
    const unsigned short* h1i = (p2 ? h1r1 : h1r0) + (size_t)bloc * TL * 256;
    unsigned short* o2o = p2 ? o2r1 : o2r0;
    const int kc = tid & 7, u = tid >> 3;

    // recurrence weights fp32 (K=64 split kc*8) + bias
    float4 wr[4][2]; float bs[4];
    const float* WR = Whh2 + dir * 16384;
    #pragma unroll
    for (int tgt = 0; tgt < 4; ++tgt){
      const int row = tgt * 64 + u;
      wr[tgt][0] = *(const float4*)(WR + row * 64 + kc * 8);
      wr[tgt][1] = *(const float4*)(WR + row * 64 + kc * 8 + 4);
      bs[tgt] = bih2[dir * 256 + row] + bhh2[dir * 256 + row];
    }
    // MFMA B-frags: wave wv owns gate tiles {2wv, 2wv+1}; B[n][k] = Wih2[n][k]
    bfx8 Bf[2][8];
    const float* WP = Wih2 + dir * 65536;
    #pragma unroll
    for (int ntl = 0; ntl < 2; ++ntl){
      const int n = (2 * wv + ntl) * 16 + (lane & 15);
      #pragma unroll
      for (int Kf = 0; Kf < 8; ++Kf)
        Bf[ntl][Kf] = pack8(WP + n * 256 + Kf * 32 + (lane >> 4) * 8);
    }
    float* xs  = (float*)smem;                   // 2 bufs x 16 x 258 f
    float* h2b = (float*)(smem + 33024);         // 2 x 64 f
    if (tid < 64){ h2b[tid] = 0.0f; h2b[64 + tid] = 0.0f; }

    auto loadA = [&](int blk, uint4* a8){
      const int m  = lane & 15;
      const int pt = dir ? (TL - 1 - (blk * 16 + m)) : (blk * 16 + m);
      const unsigned short* base = h1i + (size_t)pt * 256 + (lane >> 4) * 8;
      #pragma unroll
      for (int Kf = 0; Kf < 8; ++Kf) a8[Kf] = *(const uint4*)(base + Kf * 32);
    };
    auto domfma = [&](uint4* a8, int buf){
      fx4 acc0 = {0.f,0.f,0.f,0.f}, acc1 = {0.f,0.f,0.f,0.f};
      #pragma unroll
      for (int Kf = 0; Kf < 8; ++Kf){
        bfx8 av; __builtin_memcpy(&av, &a8[Kf], 16);
        acc0 = __builtin_amdgcn_mfma_f32_16x16x32_bf16(av, Bf[0][Kf], acc0, 0, 0, 0);
        acc1 = __builtin_amdgcn_mfma_f32_16x16x32_bf16(av, Bf[1][Kf], acc1, 0, 0, 0);
      }
      const int c0 = (2 * wv) * 16 + (lane & 15);
      #pragma unroll
      for (int rr = 0; rr < 4; ++rr){
        const int row = (lane >> 4) * 4 + rr;
        xs[buf * 4128 + row * 258 + c0]      = acc0[rr];
        xs[buf * 4128 + row * 258 + c0 + 16] = acc1[rr];
      }
    };

    uint4 a8[8];
    loadA(0, a8); domfma(a8, 0);
    loadA(1, a8); domfma(a8, 1);
    __syncthreads();

    float cst = 0.0f;
    uint4 pf[8];
    for (int B = 0; B < 128; ++B){
      if (B + 2 < 128) loadA(B + 2, pf);      // issue; consumed after the 16 steps
      const int pb = B & 1;
      for (int s = 0; s < 16; ++s){
        const int t  = B * 16 + s;
        const int tt = dir ? (TL - 1 - t) : t;
        const int cur = t & 1;
        const float4* hv4 = (const float4*)(h2b + cur * 64) + kc * 2;
        const float4 hA = hv4[0], hB = hv4[1];
        float a0 = dot4(wr[0][1], hB, dot4(wr[0][0], hA, 0.f));
        float a1 = dot4(wr[1][1], hB, dot4(wr[1][0], hA, 0.f));
        float a2 = dot4(wr[2][1], hB, dot4(wr[2][0], hA, 0.f));
        float a3 = dot4(wr[3][1], hB, dot4(wr[3][0], hA, 0.f));
        a0 = swz4_add(dpp_xadd<0x4E>(dpp_xadd<0xB1>(a0)));
        a1 = swz4_add(dpp_xadd<0x4E>(dpp_xadd<0xB1>(a1)));
        a2 = swz4_add(dpp_xadd<0x4E>(dpp_xadd<0xB1>(a2)));
        a3 = swz4_add(dpp_xadd<0x4E>(dpp_xadd<0xB1>(a3)));
        if (kc == 0){
          const float* xr = xs + pb * 4128 + s * 258 + u;
          const float ig = sigf(a0 + xr[0]   + bs[0]);
          const float fg = sigf(a1 + xr[64]  + bs[1]);
          const float gg = tanhff(a2 + xr[128] + bs[2]);
          const float og = sigf(a3 + xr[192] + bs[3]);
          cst = fmaf(fg, cst, ig * gg);
          const float h = og * tanhff(cst);
          h2b[(cur ^ 1) * 64 + u] = h;
          o2o[((size_t)bloc * TL + tt) * 128 + dir * 64 + u] = f2bf(h);
        }
        barrier_lgkm();
      }
      if (B + 2 < 128) domfma(pf, pb);        // fills buf pb for block B+2
    }

  } else {
    // ================= L3: H=16; proj (K=128) via MFMA; T-mean in regs. ====
    // WG = 4 chains (same dir). 2 waves per chain.
    const int i3 = bid - nL1 - nL2;
    const int dir = i3 & 1, q4 = i3 >> 1;
    const int grp = tid >> 7, lt = tid & 127;
    const int bloc = q4 * 4 + grp;
    const unsigned short* o2i = (p3 ? o2r1 : o2r0) + (size_t)bloc * TL * 128;
    const int u = lt >> 3, j = lt & 7, gt = j >> 1, kc = j & 1;
    const int half = wv & 1;

    const float* WR = Whh3 + dir * 1024;
    const int r = gt * 16 + u;
    const float4 wr0 = *(const float4*)(WR + r * 16 + kc * 8);
    const float4 wr1 = *(const float4*)(WR + r * 16 + kc * 8 + 4);
    const float bsv = bih3[dir * 64 + r] + bhh3[dir * 64 + r];
    const int ubase = lane & ~7;
    const float bI = bperm(bsv, ubase + 0), bF = bperm(bsv, ubase + 2);
    const float bG = bperm(bsv, ubase + 4), bO = bperm(bsv, ubase + 6);

    bfx8 Bf[2][4];
    const float* WP = Wih3 + dir * 8192;     // (64,128)
    #pragma unroll
    for (int ntl = 0; ntl < 2; ++ntl){
      const int n = (2 * half + ntl) * 16 + (lane & 15);
      #pragma unroll
      for (int Kf = 0; Kf < 4; ++Kf)
        Bf[ntl][Kf] = pack8(WP + n * 128 + Kf * 32 + (lane >> 4) * 8);
    }
    float* xs  = (float*)smem + grp * 2112;  // per chain: 2 bufs x 16 x 66 f
    float* h3b = (float*)(smem + 33792) + grp * 32;
    if (lt < 32) h3b[lt] = 0.0f;

    auto loadA3 = [&](int blk, uint4* a4){
      const int m  = lane & 15;
      const int pt = dir ? (TL - 1 - (blk * 16 + m)) : (blk * 16 + m);
      const unsigned short* base = o2i + (size_t)pt * 128 + (lane >> 4) * 8;
      #pragma unroll
      for (int Kf = 0; Kf < 4; ++Kf) a4[Kf] = *(const uint4*)(base + Kf * 32);
    };
    auto domfma3 = [&](uint4* a4, int buf){
      fx4 acc0 = {0.f,0.f,0.f,0.f}, acc1 = {0.f,0.f,0.f,0.f};
      #pragma unroll
      for (int Kf = 0; Kf < 4; ++Kf){
        bfx8 av; __builtin_memcpy(&av, &a4[Kf], 16);
        acc0 = __builtin_amdgcn_mfma_f32_16x16x32_bf16(av, Bf[0][Kf], acc0, 0, 0, 0);
        acc1 = __builtin_amdgcn_mfma_f32_16x16x32_bf16(av, Bf[1][Kf], acc1, 0, 0, 0);
      }
      const int c0 = (2 * half) * 16 + (lane & 15);
      #pragma unroll
      for (int rr = 0; rr < 4; ++rr){
        const int row = (lane >> 4) * 4 + rr;
        xs[buf * 1056 + row * 66 + c0]      = acc0[rr];
        xs[buf * 1056 + row * 66 + c0 + 16] = acc1[rr];
      }
    };

    uint4 a4[4];
    loadA3(0, a4); domfma3(a4, 0);
    loadA3(1, a4); domfma3(a4, 1);
    __syncthreads();

    float cst = 0.0f, msum = 0.0f;
    uint4 pf[4];
    for (int B = 0; B < 128; ++B){
      if (B + 2 < 128) loadA3(B + 2, pf);
      const int pb = B & 1;
      for (int s = 0; s < 16; ++s){
        const int t = B * 16 + s;
        const int cur = t & 1;
        const float4* h3p = (const float4*)(h3b + cur * 16 + kc * 8);
        float acc = dot4(wr1, h3p[1], dot4(wr0, h3p[0], 0.f));
        acc = dpp_xadd<0xB1>(acc);
        const float gI = bperm(acc, ubase + 0), gF = bperm(acc, ubase + 2);
        const float gG = bperm(acc, ubase + 4), gO = bperm(acc, ubase + 6);
        if (j == 0){
          const float* xr = xs + pb * 1056 + s * 66 + u;
          const float ig = sigf(gI + bI + xr[0]);
          const float fg = sigf(gF + bF + xr[16]);
          const float gg = tanhff(gG + bG + xr[32]);
          const float og = sigf(gO + bO + xr[48]);
          cst = fmaf(fg, cst, ig * gg);
          const float h = og * tanhff(cst);
          h3b[(cur ^ 1) * 16 + u] = h;
          msum += h;
        }
        barrier_lgkm();
      }
      if (B + 2 < 128) domfma3(pf, pb);
    }
    if (j == 0) sums[(size_t)(cb3 + bloc) * 32 + dir * 16 + u] = msum;
  }
}

// ---------------- head: mean (pre-summed) + MLP, one 64-thr WG per batch
__global__ __launch_bounds__(64) void head_kernel(
    const float* __restrict__ sums,
    const float* __restrict__ hW1, const float* __restrict__ hb1,
    const float* __restrict__ hW2, const float* __restrict__ hb2,
    const float* __restrict__ hW3, const float* __restrict__ hb3,
    float* __restrict__ out)
{
  __shared__ float m[32], h1s[64], h2s[16];
  const int tid = threadIdx.x, b = blockIdx.x;
  if (tid < 32) m[tid] = sums[b * 32 + tid] * (1.0f / 2048.0f);
  __syncthreads();
  {
    float a = hb1[tid];
    #pragma unroll
    for (int k = 0; k < 32; ++k) a = fmaf(m[k], hW1[tid * 32 + k], a);
    h1s[tid] = fmaxf(a, 0.0f);
  }
  __syncthreads();
  if (tid < 16){
    float a = hb2[tid];
    #pragma unroll
    for (int k = 0; k < 64; ++k) a = fmaf(h1s[k], hW2[tid * 64 + k], a);
    h2s[tid] = fmaxf(a, 0.0f);
  }
  __syncthreads();
  if (tid < 20){
    float a = hb3[tid];
    #pragma unroll
    for (int k = 0; k < 16; ++k) a = fmaf(h2s[k], hW3[tid * 16 + k], a);
    out[b * 20 + tid] = a;
  }
}

extern "C" void kernel_launch(void* const* d_in, const int* in_sizes, int n_in,
                              void* d_out, int out_size, void* d_ws, size_t ws_size,
                              hipStream_t stream) {
  (void)in_sizes; (void)n_in; (void)out_size; (void)ws_size;
  const float* x    = (const float*)d_in[0];
  const float* Wih1 = (const float*)d_in[1];
  const float* Whh1 = (const float*)d_in[2];
  const float* bih1 = (const float*)d_in[3];
  const float* bhh1 = (const float*)d_in[4];
  const float* Wih2 = (const float*)d_in[5];
  const float* Whh2 = (const float*)d_in[6];
  const float* bih2 = (const float*)d_in[7];
  const float* bhh2 = (const float*)d_in[8];
  const float* Wih3 = (const float*)d_in[9];
  const float* Whh3 = (const float*)d_in[10];
  const float* bih3 = (const float*)d_in[11];
  const float* bhh3 = (const float*)d_in[12];
  const float* hW1  = (const float*)d_in[13];
  const float* hb1  = (const float*)d_in[14];
  const float* hW2  = (const float*)d_in[15];
  const float* hb2  = (const float*)d_in[16];
  const float* hW3  = (const float*)d_in[17];
  const float* hb3  = (const float*)d_in[18];

  // Workspace (151 MB used; >=167.8 MB proven available by round-2's BC=32):
  // h1 rings (48,2048,256) bf16 x2 | o2 rings (48,2048,128) bf16 x2 | sums f32
  unsigned short* h1r0 = (unsigned short*)d_ws;
  unsigned short* h1r1 = h1r0 + (size_t)48 * TL * 256;
  unsigned short* o2r0 = (unsigned short*)((unsigned char*)d_ws + 100663296u);
  unsigned short* o2r1 = o2r0 + (size_t)48 * TL * 128;
  float* sums = (float*)((unsigned char*)d_ws + 150994944u);

  const int nbs[6] = {48, 48, 48, 48, 48, 16};
  const int cbs[6] = {0, 48, 96, 144, 192, 240};
  for (int k = 0; k < 8; ++k){
    const int a1 = (k < 6) ? nbs[k] : 0;
    const int a2 = (k >= 1 && k < 7) ? nbs[k - 1] : 0;
    const int a3 = (k >= 2) ? nbs[k - 2] : 0;
    const int nL1 = 2 * a1, nL2 = 2 * a2, nL3 = a3 / 2;
    mega_kernel<<<dim3(nL1 + nL2 + nL3), dim3(512), 0, stream>>>(
        nL1, nL2, nL3,
        (k < 6) ? cbs[k] : 0, (k >= 1 && k < 7) ? cbs[k - 1] : 0,
        (k >= 2) ? cbs[k - 2] : 0,
        k & 1, (k + 1) & 1, k & 1,
        x, Wih1, Whh1, bih1, bhh1, Wih2, Whh2, bih2, bhh2,
        Wih3, Whh3, bih3, bhh3, h1r0, h1r1, o2r0, o2r1, sums);
  }
  head_kernel<<<dim3(256), dim3(64), 0, stream>>>(
      sums, hW1, hb1, hW2, hb2, hW3, hb3, (float*)d_out);
}